// Round 1
// 616.875 us; speedup vs baseline: 1.1289x; 1.1289x over previous
//
#include <hip/hip_runtime.h>
#include <stdint.h>

typedef float v4f __attribute__((ext_vector_type(4)));
typedef short v8s __attribute__((ext_vector_type(8)));

constexpr int Bq = 4, Tq = 8192, Dq = 1024, Fq = 4096;
constexpr int CAP = Tq / 2;     // 4096 tokens selected per batch row
constexpr int Mq  = Bq * CAP;   // 16384 routed tokens total

// ---------- helpers ----------
__device__ __forceinline__ unsigned short f2bf(float f) {
  unsigned int u = __float_as_uint(f);
  u += 0x7FFFu + ((u >> 16) & 1u);   // RNE
  return (unsigned short)(u >> 16);
}

__device__ __forceinline__ void async_cp16(const void* g, void* l) {
  // 16B/lane global->LDS DMA; LDS dest is wave-uniform base + lane*16
  __builtin_amdgcn_global_load_lds(
      (__attribute__((address_space(1))) void*)g,
      (__attribute__((address_space(3))) void*)l, 16, 0, 0);
}

// ---------- scores: s[b,t] = dot(x[b,t,:], w_router), fp64 accumulate ----------
__global__ void scores_kernel(const float* __restrict__ x,
                              const float* __restrict__ wr_g,
                              double* __restrict__ scores) {
  __shared__ __align__(16) float wr[Dq];
  for (int i = threadIdx.x; i < Dq; i += 256) wr[i] = wr_g[i];
  __syncthreads();
  int wid = threadIdx.x >> 6, lane = threadIdx.x & 63;
  int gw = blockIdx.x * 4 + wid;
  const float4* wp = (const float4*)wr;
  for (int rr = 0; rr < 4; ++rr) {
    int row = gw * 4 + rr;   // [0, B*T)
    const float4* xp = (const float4*)(x + (size_t)row * Dq);
    double s = 0.0;
#pragma unroll
    for (int q = 0; q < 4; ++q) {
      float4 v = xp[lane + q * 64];
      float4 w = wp[lane + q * 64];
      s += (double)v.x * w.x + (double)v.y * w.y + (double)v.z * w.z + (double)v.w * w.w;
    }
#pragma unroll
    for (int off = 32; off; off >>= 1) s += __shfl_down(s, off);
    if (lane == 0) scores[row] = s;
  }
}

// ---------- top-k select (exact, per batch row) ----------
__device__ __forceinline__ int block_reduce_i(int v, int* red, int tid) {
#pragma unroll
  for (int off = 32; off; off >>= 1) v += __shfl_down(v, off);
  __syncthreads();                       // protect red[] from previous call
  if ((tid & 63) == 0) red[tid >> 6] = v;
  __syncthreads();
  int s = 0;
#pragma unroll
  for (int k = 0; k < 16; ++k) s += red[k];
  return s;                              // same value in all threads
}

__global__ __launch_bounds__(1024) void select_topk(const double* __restrict__ scores,
                                                    int* __restrict__ selIdx,
                                                    unsigned char* __restrict__ selFlag) {
  int b = blockIdx.x, tid = threadIdx.x;
  const double* s = scores + (size_t)b * Tq;
  __shared__ int red[16];
  __shared__ int counter;
  unsigned long long key[8];
#pragma unroll
  for (int i = 0; i < 8; ++i) {
    unsigned long long u = (unsigned long long)__double_as_longlong(s[tid + i * 1024]);
    key[i] = (u >> 63) ? ~u : (u | 0x8000000000000000ULL);  // order-preserving map
  }
  // cutoff = max X with count(key >= X) >= CAP  (== CAP-th largest key)
  unsigned long long cutoff = 0ULL;
  for (int bit = 63; bit >= 0; --bit) {
    unsigned long long cand = cutoff | (1ULL << bit);
    int c = 0;
#pragma unroll
    for (int i = 0; i < 8; ++i) c += (key[i] >= cand) ? 1 : 0;
    int tot = block_reduce_i(c, red, tid);
    if (tot >= CAP) cutoff = cand;
  }
  int cGt = 0, cEq = 0;
#pragma unroll
  for (int i = 0; i < 8; ++i) { cGt += (key[i] > cutoff); cEq += (key[i] == cutoff); }
  int gtTot = block_reduce_i(cGt, red, tid);
  int eqTot = block_reduce_i(cEq, red, tid);
  int need = CAP - gtTot;                // ties to take (>=1)
  if (tid == 0) counter = 0;
  __syncthreads();
  bool takeAllEq = (eqTot == need);      // common case: no straddling duplicates
#pragma unroll
  for (int i = 0; i < 8; ++i) {
    int t = tid + i * 1024;
    bool sel = takeAllEq ? (key[i] >= cutoff) : (key[i] > cutoff);
    if (sel) { int pos = atomicAdd(&counter, 1); selIdx[b * CAP + pos] = t; }
    selFlag[(size_t)b * Tq + t] = sel ? (unsigned char)1 : (unsigned char)0;
  }
  if (!takeAllEq) {                      // rare: exact ties at cutoff, lowest index first
    __syncthreads();
    if (tid == 0) {
      int taken = 0;
      for (int t = 0; t < Tq && taken < need; ++t) {
        unsigned long long u = (unsigned long long)__double_as_longlong(s[t]);
        unsigned long long k = (u >> 63) ? ~u : (u | 0x8000000000000000ULL);
        if (k == cutoff) {
          selIdx[b * CAP + gtTot + taken] = t;
          selFlag[(size_t)b * Tq + t] = 1;
          ++taken;
        }
      }
    }
  }
}

// ---------- gather selected rows -> bf16 Xs [Mq, Dq] ----------
__global__ void gather_kernel(const float* __restrict__ x,
                              const int* __restrict__ selIdx,
                              unsigned short* __restrict__ Xs) {
  int wid = threadIdx.x >> 6, lane = threadIdx.x & 63;
  int m = blockIdx.x * 4 + wid;          // [0, Mq)
  int b = m >> 12;                       // CAP == 4096
  int tok = selIdx[m];
  const float4* src = (const float4*)(x + ((size_t)b * Tq + tok) * Dq);
  ushort4* dst = (ushort4*)(Xs + (size_t)m * Dq);
#pragma unroll
  for (int q = 0; q < 4; ++q) {
    float4 v = src[lane + q * 64];
    ushort4 o; o.x = f2bf(v.x); o.y = f2bf(v.y); o.z = f2bf(v.z); o.w = f2bf(v.w);
    dst[lane + q * 64] = o;
  }
}

// ---------- pass-through copy of unselected rows ----------
__global__ void copy_pass(const float* __restrict__ x,
                          const unsigned char* __restrict__ selFlag,
                          float* __restrict__ out) {
  int wid = threadIdx.x >> 6, lane = threadIdx.x & 63;
  int row = blockIdx.x * 4 + wid;        // [0, B*T)
  if (selFlag[row]) return;              // wave-uniform branch
  const float4* src = (const float4*)(x + (size_t)row * Dq);
  float4* dst = (float4*)(out + (size_t)row * Dq);
#pragma unroll
  for (int q = 0; q < 4; ++q) dst[lane + q * 64] = src[lane + q * 64];
}

// ---------- fp32 [R,C] -> bf16 transposed [C,R] ----------
__global__ void transpose_f32_to_bf16(const float* __restrict__ in,
                                      unsigned short* __restrict__ out,
                                      int R, int C) {
  __shared__ float tile[32][33];
  int tx = threadIdx.x, ty = threadIdx.y;          // (32, 8)
  int c0 = blockIdx.x * 32, r0 = blockIdx.y * 32;
#pragma unroll
  for (int k = 0; k < 4; ++k)
    tile[ty + k * 8][tx] = in[(size_t)(r0 + ty + k * 8) * C + c0 + tx];
  __syncthreads();
#pragma unroll
  for (int k = 0; k < 4; ++k)
    out[(size_t)(c0 + ty + k * 8) * R + r0 + tx] = f2bf(tile[tx][ty + k * 8]);
}

// ============================================================================
// 256x256-tile, BK=64, 8-wave (2Mx4N), 8-phase schedule with counted vmcnt.
//
// LDS: A/B each [2 buf][256 rows][64 k] bf16 = 64 KiB -> 128 KiB total.
// Tile t lives in buf[t&1].  Each K-tile = 4 compute phases:
//   P0: ds_read A-msub0(8xb128)+B-nsub0(4), mfma quad (i0..3, j0..1)
//   P1: ds_read B-nsub1(4),                 mfma (i0..3, j2..3)
//   P2: ds_read A-msub1(8),                 mfma (i4..7, j0..1)   [B j0..1 in regs]
//   P3: (no reads),                         mfma (i4..7, j2..3)   [B j2..3 in regs]
// Staging is quarter-granular (64 rows = 512 thr x 16B = one global_load_lds
// sweep).  Quarters of tile t+2 are staged into buf[t&1] during tile t's
// phases, each only after its region's last ds_read (barrier-separated):
//   P0: A-Q1,Q3 of t+1 | P1: A-Q0,Q2 of t+2 | P2: B-Q0,Q1 of t+2 | P3: B-Q2,Q3
// One counted wait per tile at P3: vmcnt(6) (= the 6 loads of phases P1..P3)
// guarantees tile t+1 fully resident; never drains to 0 in steady state.
// Swizzle: LDS slot (row, c) holds global 16B-chunk (c ^ (row&7)); reads use
// the same XOR -> 8 slots x 8 lanes = all 32 banks (0-conflict pattern).
// ============================================================================

#define MFMA1(i, j, a, b) acc[i][j] = __builtin_amdgcn_mfma_f32_16x16x32_bf16(a, b, acc[i][j], 0, 0, 0)
#define MMQ(ib, jb, AF, BF) do { \
  MFMA1((ib)+0,(jb)+0,AF[0][0],BF[0][0]); MFMA1((ib)+0,(jb)+1,AF[0][0],BF[1][0]); \
  MFMA1((ib)+1,(jb)+0,AF[1][0],BF[0][0]); MFMA1((ib)+1,(jb)+1,AF[1][0],BF[1][0]); \
  MFMA1((ib)+2,(jb)+0,AF[2][0],BF[0][0]); MFMA1((ib)+2,(jb)+1,AF[2][0],BF[1][0]); \
  MFMA1((ib)+3,(jb)+0,AF[3][0],BF[0][0]); MFMA1((ib)+3,(jb)+1,AF[3][0],BF[1][0]); \
  MFMA1((ib)+0,(jb)+0,AF[0][1],BF[0][1]); MFMA1((ib)+0,(jb)+1,AF[0][1],BF[1][1]); \
  MFMA1((ib)+1,(jb)+0,AF[1][1],BF[0][1]); MFMA1((ib)+1,(jb)+1,AF[1][1],BF[1][1]); \
  MFMA1((ib)+2,(jb)+0,AF[2][1],BF[0][1]); MFMA1((ib)+2,(jb)+1,AF[2][1],BF[1][1]); \
  MFMA1((ib)+3,(jb)+0,AF[3][1],BF[0][1]); MFMA1((ib)+3,(jb)+1,AF[3][1],BF[1][1]); \
} while (0)

#define LDSA(dst, i, kk, bo) dst = *(const v8s*)(As + (bo) + ((aRdB + (i) * 1024) ^ ((kk) * 32)))
#define LDSB(dst, j, kk, bo) dst = *(const v8s*)(Bs + (bo) + ((bRdB + (j) * 1024) ^ ((kk) * 32)))

#define RD_A_LO(bo) do { LDSA(afr[0][0],0,0,bo); LDSA(afr[0][1],0,1,bo); \
                         LDSA(afr[1][0],1,0,bo); LDSA(afr[1][1],1,1,bo); \
                         LDSA(afr[2][0],2,0,bo); LDSA(afr[2][1],2,1,bo); \
                         LDSA(afr[3][0],3,0,bo); LDSA(afr[3][1],3,1,bo); } while (0)
#define RD_A_HI(bo) do { LDSA(afr[0][0],4,0,bo); LDSA(afr[0][1],4,1,bo); \
                         LDSA(afr[1][0],5,0,bo); LDSA(afr[1][1],5,1,bo); \
                         LDSA(afr[2][0],6,0,bo); LDSA(afr[2][1],6,1,bo); \
                         LDSA(afr[3][0],7,0,bo); LDSA(afr[3][1],7,1,bo); } while (0)
#define RD_B_LO(bo) do { LDSB(bfrA[0][0],0,0,bo); LDSB(bfrA[0][1],0,1,bo); \
                         LDSB(bfrA[1][0],1,0,bo); LDSB(bfrA[1][1],1,1,bo); } while (0)
#define RD_B_HI(bo) do { LDSB(bfrB[0][0],2,0,bo); LDSB(bfrB[0][1],2,1,bo); \
                         LDSB(bfrB[1][0],3,0,bo); LDSB(bfrB[1][1],3,1,bo); } while (0)

#define STG_A(qtr, t, bo) async_cp16(aSrc + (size_t)(qtr) * 64 * K + (size_t)(t) * 64, aDst + (bo) + (qtr) * 4096)
#define STG_B(qtr, t, bo) async_cp16(bSrc + (size_t)(qtr) * 64 * K + (size_t)(t) * 64, bDst + (bo) + (qtr) * 4096)

#define BARR() __builtin_amdgcn_s_barrier()
#define WAITV(n) asm volatile("s_waitcnt vmcnt(" #n ")" ::: "memory")

template<int K, int NTN, bool IS_G1>
__global__ __launch_bounds__(512, 2)
void gemm_8ph(const unsigned short* __restrict__ A,   // [rows, K] bf16
              const unsigned short* __restrict__ Bt,  // [N, K] bf16
              const float* __restrict__ bias,
              unsigned short* __restrict__ Hout,      // IS_G1: [rows, Fq] bf16
              const int* __restrict__ selIdx,         // !IS_G1
              float* __restrict__ out,                // !IS_G1
              int chunkStart) {
  constexpr int NT = K / 64;   // K-tiles
  constexpr int NI = NT / 2;   // 8-phase iterations
  __shared__ __align__(16) unsigned short As[2 * 256 * 64];
  __shared__ __align__(16) unsigned short Bs[2 * 256 * 64];

  const int tid = threadIdx.x;
  const int wid = tid >> 6, lane = tid & 63;
  const int wm = wid >> 2, wn = wid & 3;          // 2 x 4 wave grid
  const int quad = lane >> 4, l16 = lane & 15;

  // bijective XCD swizzle (m204 variant; valid for any grid size)
  const int nwg = gridDim.x;
  const int qq = nwg >> 3, rr = nwg & 7;
  const int xcd = blockIdx.x & 7, loc = blockIdx.x >> 3;
  const int s = (xcd < rr ? xcd * (qq + 1) : rr * (qq + 1) + (xcd - rr) * qq) + loc;
  const int pIdx = s / NTN, nIdx = s % NTN;
  const int m0 = pIdx * 256, n0 = nIdx * 256;

  // ---- staging addressing (pre-swizzled global source, linear LDS dest) ----
  const int sr = tid >> 3;                        // row within 64-row quarter
  const int sc = (tid & 7) ^ (sr & 7);            // swizzled source 16B chunk
  const unsigned short* aSrc = A  + (size_t)(m0 + sr) * K + sc * 8;
  const unsigned short* bSrc = Bt + (size_t)(n0 + sr) * K + sc * 8;
  unsigned short* aDst = As + wid * 512;          // wave-uniform LDS base
  unsigned short* bDst = Bs + wid * 512;

  // ---- read addressing (shorts): row*64 + (chunk ^ (row&7))*8, kk flips bit5
  const int swz = (quad ^ (l16 & 7)) * 8;
  const int aRdB = (wm * 128 + l16) * 64 + swz;
  const int bRdB = (wn * 64 + l16) * 64 + swz;

  v4f acc[8][4] = {};
  v8s afr[4][2], bfrA[2][2], bfrB[2][2];

  // ---- prologue: tile0 fully (8 loads, buf0); tile1 A-Q0,Q2 + B-Q0..Q3 (6, buf1)
  STG_A(0, 0, 0); STG_A(1, 0, 0); STG_A(2, 0, 0); STG_A(3, 0, 0);
  STG_B(0, 0, 0); STG_B(1, 0, 0); STG_B(2, 0, 0); STG_B(3, 0, 0);
  STG_A(0, 1, 16384); STG_A(2, 1, 16384);
  STG_B(0, 1, 16384); STG_B(1, 1, 16384); STG_B(2, 1, 16384); STG_B(3, 1, 16384);
  WAITV(6);            // tile0 resident; tile1's 6 may stay in flight
  BARR();

  // even tiles -> buf0 (bo=0), odd tiles -> buf1 (bo=16384): compile-time
  for (int it = 0; it < NI - 1; ++it) {
    const int t0 = 2 * it;
    // phase 0 (tile t0)
    RD_A_LO(0); RD_B_LO(0);
    STG_A(1, t0 + 1, 16384); STG_A(3, t0 + 1, 16384);
    BARR(); __builtin_amdgcn_s_setprio(1); MMQ(0, 0, afr, bfrA); __builtin_amdgcn_s_setprio(0); BARR();
    // phase 1
    RD_B_HI(0);
    STG_A(0, t0 + 2, 0); STG_A(2, t0 + 2, 0);
    BARR(); __builtin_amdgcn_s_setprio(1); MMQ(0, 2, afr, bfrB); __builtin_amdgcn_s_setprio(0); BARR();
    // phase 2
    RD_A_HI(0);
    STG_B(0, t0 + 2, 0); STG_B(1, t0 + 2, 0);
    BARR(); __builtin_amdgcn_s_setprio(1); MMQ(4, 0, afr, bfrA); __builtin_amdgcn_s_setprio(0); BARR();
    // phase 3: counted wait -> tile t0+1 fully resident
    STG_B(2, t0 + 2, 0); STG_B(3, t0 + 2, 0);
    WAITV(6);
    BARR(); __builtin_amdgcn_s_setprio(1); MMQ(4, 2, afr, bfrB); __builtin_amdgcn_s_setprio(0); BARR();
    // phase 4 (tile t0+1)
    RD_A_LO(16384); RD_B_LO(16384);
    STG_A(1, t0 + 2, 0); STG_A(3, t0 + 2, 0);
    BARR(); __builtin_amdgcn_s_setprio(1); MMQ(0, 0, afr, bfrA); __builtin_amdgcn_s_setprio(0); BARR();
    // phase 5
    RD_B_HI(16384);
    STG_A(0, t0 + 3, 16384); STG_A(2, t0 + 3, 16384);
    BARR(); __builtin_amdgcn_s_setprio(1); MMQ(0, 2, afr, bfrB); __builtin_amdgcn_s_setprio(0); BARR();
    // phase 6
    RD_A_HI(16384);
    STG_B(0, t0 + 3, 16384); STG_B(1, t0 + 3, 16384);
    BARR(); __builtin_amdgcn_s_setprio(1); MMQ(4, 0, afr, bfrA); __builtin_amdgcn_s_setprio(0); BARR();
    // phase 7: counted wait -> tile t0+2 fully resident
    STG_B(2, t0 + 3, 16384); STG_B(3, t0 + 3, 16384);
    WAITV(6);
    BARR(); __builtin_amdgcn_s_setprio(1); MMQ(4, 2, afr, bfrB); __builtin_amdgcn_s_setprio(0); BARR();
  }

  { // ---- last iteration: tiles NT-2 (buf0), NT-1 (buf1); drain ----
    RD_A_LO(0); RD_B_LO(0);
    STG_A(1, NT - 1, 16384); STG_A(3, NT - 1, 16384);   // final 2 quarters
    BARR(); __builtin_amdgcn_s_setprio(1); MMQ(0, 0, afr, bfrA); __builtin_amdgcn_s_setprio(0); BARR();
    RD_B_HI(0);
    BARR(); __builtin_amdgcn_s_setprio(1); MMQ(0, 2, afr, bfrB); __builtin_amdgcn_s_setprio(0); BARR();
    RD_A_HI(0);
    BARR(); __builtin_amdgcn_s_setprio(1); MMQ(4, 0, afr, bfrA); __builtin_amdgcn_s_setprio(0); BARR();
    WAITV(0);                                           // tile NT-1 resident
    BARR(); __builtin_amdgcn_s_setprio(1); MMQ(4, 2, afr, bfrB); __builtin_amdgcn_s_setprio(0); BARR();
    RD_A_LO(16384); RD_B_LO(16384);
    BARR(); __builtin_amdgcn_s_setprio(1); MMQ(0, 0, afr, bfrA); __builtin_amdgcn_s_setprio(0); BARR();
    RD_B_HI(16384);
    BARR(); __builtin_amdgcn_s_setprio(1); MMQ(0, 2, afr, bfrB); __builtin_amdgcn_s_setprio(0); BARR();
    RD_A_HI(16384);
    BARR(); __builtin_amdgcn_s_setprio(1); MMQ(4, 0, afr, bfrA); __builtin_amdgcn_s_setprio(0); BARR();
    __builtin_amdgcn_s_setprio(1); MMQ(4, 2, afr, bfrB); __builtin_amdgcn_s_setprio(0);
  }

  // ---- epilogue ----
  const int mB = m0 + wm * 128, nB = n0 + wn * 64;
  float bv[4];
#pragma unroll
  for (int j = 0; j < 4; ++j) bv[j] = bias[nB + j * 16 + l16];

  if constexpr (IS_G1) {
    const float kA = 0.7978845608028654f, kB2 = 0.044715f * 0.7978845608028654f;
    const float kE = -2.0f * 1.4426950408889634f;   // exp(-2z) = exp2(kE*z)
#pragma unroll
    for (int i = 0; i < 8; ++i)
#pragma unroll
      for (int r = 0; r < 4; ++r) {
        const int row = mB + i * 16 + quad * 4 + r;
        unsigned short* hp = Hout + (size_t)row * Fq;
#pragma unroll
        for (int j = 0; j < 4; ++j) {
          float c = acc[i][j][r] + bv[j];
          float z = c * __builtin_fmaf(kB2, c * c, kA);
          float a = exp2f(kE * fabsf(z));
          float th = copysignf((1.0f - a) * __builtin_amdgcn_rcpf(1.0f + a), z);
          hp[nB + j * 16 + l16] = f2bf(0.5f * c * (1.0f + th));
        }
      }
  } else {
#pragma unroll
    for (int i = 0; i < 8; ++i)
#pragma unroll
      for (int r = 0; r < 4; ++r) {
        const int lrow = mB + i * 16 + quad * 4 + r;
        const int m = chunkStart + lrow;
        const int b = m >> 12;             // CAP == 4096
        const int tok = selIdx[m];
        float* op = out + ((size_t)b * Tq + tok) * Dq;
#pragma unroll
        for (int j = 0; j < 4; ++j)
          op[nB + j * 16 + l16] = acc[i][j][r] + bv[j];
      }
  }
}

// ---------- host ----------
extern "C" void kernel_launch(void* const* d_in, const int* in_sizes, int n_in,
                              void* d_out, int out_size, void* d_ws, size_t ws_size,
                              hipStream_t stream) {
  const float* x        = (const float*)d_in[0];
  const float* w_router = (const float*)d_in[1];
  const float* w1       = (const float*)d_in[2];
  const float* b1       = (const float*)d_in[3];
  const float* w2       = (const float*)d_in[4];
  const float* b2       = (const float*)d_in[5];
  float* out = (float*)d_out;

  char* p = (char*)d_ws;
  auto alloc = [&](size_t bytes) {
    char* r = p;
    p += (bytes + 255) & ~(size_t)255;
    return r;
  };
  double* scores          = (double*)alloc((size_t)Bq * Tq * 8);
  int* selIdx             = (int*)alloc((size_t)Mq * 4);
  unsigned char* selFlag  = (unsigned char*)alloc((size_t)Bq * Tq);
  unsigned short* W1t     = (unsigned short*)alloc((size_t)Dq * Fq * 2);  // [F, D]
  unsigned short* W2t     = (unsigned short*)alloc((size_t)Dq * Fq * 2);  // [D, F]
  unsigned short* Xs      = (unsigned short*)alloc((size_t)Mq * Dq * 2);  // [M, D]
  size_t used = (size_t)(p - (char*)d_ws);
  size_t rem = ws_size > used ? ws_size - used : 0;
  int chunkRows = (int)(rem / ((size_t)Fq * 2));
  chunkRows = (chunkRows / 256) * 256;
  if (chunkRows > Mq) chunkRows = Mq;
  if (chunkRows < 256) chunkRows = 256;   // requires ws_size >= ~51 MB
  unsigned short* H = (unsigned short*)p;  // [chunkRows, F] bf16

  transpose_f32_to_bf16<<<dim3(Fq / 32, Dq / 32), dim3(32, 8), 0, stream>>>(w1, W1t, Dq, Fq);
  transpose_f32_to_bf16<<<dim3(Dq / 32, Fq / 32), dim3(32, 8), 0, stream>>>(w2, W2t, Fq, Dq);
  scores_kernel<<<2048, 256, 0, stream>>>(x, w_router, scores);
  select_topk<<<Bq, 1024, 0, stream>>>(scores, selIdx, selFlag);
  gather_kernel<<<Mq / 4, 256, 0, stream>>>(x, selIdx, Xs);
  copy_pass<<<(Bq * Tq) / 4, 256, 0, stream>>>(x, selFlag, out);

  for (int r0 = 0; r0 < Mq; r0 += chunkRows) {
    int rows = (Mq - r0 < chunkRows) ? (Mq - r0) : chunkRows;
    int p1 = rows / 256;
    gemm_8ph<Dq, Fq / 256, true><<<p1 * (Fq / 256), 512, 0, stream>>>(
        Xs + (size_t)r0 * Dq, W1t, b1, H, nullptr, nullptr, 0);
    gemm_8ph<Fq, Dq / 256, false><<<p1 * (Dq / 256), 512, 0, stream>>>(
        H, W2t, b2, nullptr, selIdx, out, r0);
  }
}

// Round 2
// 616.271 us; speedup vs baseline: 1.1300x; 1.0010x over previous
//
#include <hip/hip_runtime.h>
#include <stdint.h>

typedef float v4f __attribute__((ext_vector_type(4)));
typedef short v8s __attribute__((ext_vector_type(8)));

constexpr int Bq = 4, Tq = 8192, Dq = 1024, Fq = 4096;
constexpr int CAP = Tq / 2;     // 4096 tokens selected per batch row
constexpr int Mq  = Bq * CAP;   // 16384 routed tokens total

// ---------- helpers ----------
__device__ __forceinline__ unsigned short f2bf(float f) {
  unsigned int u = __float_as_uint(f);
  u += 0x7FFFu + ((u >> 16) & 1u);   // RNE
  return (unsigned short)(u >> 16);
}

__device__ __forceinline__ void async_cp16(const void* g, void* l) {
  // 16B/lane global->LDS DMA; LDS dest is wave-uniform base + lane*16
  __builtin_amdgcn_global_load_lds(
      (__attribute__((address_space(1))) void*)g,
      (__attribute__((address_space(3))) void*)l, 16, 0, 0);
}

// ---------- scores: s[b,t] = dot(x[b,t,:], w_router), fp64 accumulate ----------
__global__ void scores_kernel(const float* __restrict__ x,
                              const float* __restrict__ wr_g,
                              double* __restrict__ scores) {
  __shared__ __align__(16) float wr[Dq];
  for (int i = threadIdx.x; i < Dq; i += 256) wr[i] = wr_g[i];
  __syncthreads();
  int wid = threadIdx.x >> 6, lane = threadIdx.x & 63;
  int gw = blockIdx.x * 4 + wid;
  const float4* wp = (const float4*)wr;
  for (int rr = 0; rr < 4; ++rr) {
    int row = gw * 4 + rr;   // [0, B*T)
    const float4* xp = (const float4*)(x + (size_t)row * Dq);
    double s = 0.0;
#pragma unroll
    for (int q = 0; q < 4; ++q) {
      float4 v = xp[lane + q * 64];
      float4 w = wp[lane + q * 64];
      s += (double)v.x * w.x + (double)v.y * w.y + (double)v.z * w.z + (double)v.w * w.w;
    }
#pragma unroll
    for (int off = 32; off; off >>= 1) s += __shfl_down(s, off);
    if (lane == 0) scores[row] = s;
  }
}

// ---------- top-k select (exact, per batch row) ----------
__device__ __forceinline__ int block_reduce_i(int v, int* red, int tid) {
#pragma unroll
  for (int off = 32; off; off >>= 1) v += __shfl_down(v, off);
  __syncthreads();                       // protect red[] from previous call
  if ((tid & 63) == 0) red[tid >> 6] = v;
  __syncthreads();
  int s = 0;
#pragma unroll
  for (int k = 0; k < 16; ++k) s += red[k];
  return s;                              // same value in all threads
}

__global__ __launch_bounds__(1024) void select_topk(const double* __restrict__ scores,
                                                    int* __restrict__ selIdx,
                                                    unsigned char* __restrict__ selFlag) {
  int b = blockIdx.x, tid = threadIdx.x;
  const double* s = scores + (size_t)b * Tq;
  __shared__ int red[16];
  __shared__ int counter;
  unsigned long long key[8];
#pragma unroll
  for (int i = 0; i < 8; ++i) {
    unsigned long long u = (unsigned long long)__double_as_longlong(s[tid + i * 1024]);
    key[i] = (u >> 63) ? ~u : (u | 0x8000000000000000ULL);  // order-preserving map
  }
  // cutoff = max X with count(key >= X) >= CAP  (== CAP-th largest key)
  unsigned long long cutoff = 0ULL;
  for (int bit = 63; bit >= 0; --bit) {
    unsigned long long cand = cutoff | (1ULL << bit);
    int c = 0;
#pragma unroll
    for (int i = 0; i < 8; ++i) c += (key[i] >= cand) ? 1 : 0;
    int tot = block_reduce_i(c, red, tid);
    if (tot >= CAP) cutoff = cand;
  }
  int cGt = 0, cEq = 0;
#pragma unroll
  for (int i = 0; i < 8; ++i) { cGt += (key[i] > cutoff); cEq += (key[i] == cutoff); }
  int gtTot = block_reduce_i(cGt, red, tid);
  int eqTot = block_reduce_i(cEq, red, tid);
  int need = CAP - gtTot;                // ties to take (>=1)
  if (tid == 0) counter = 0;
  __syncthreads();
  bool takeAllEq = (eqTot == need);      // common case: no straddling duplicates
#pragma unroll
  for (int i = 0; i < 8; ++i) {
    int t = tid + i * 1024;
    bool sel = takeAllEq ? (key[i] >= cutoff) : (key[i] > cutoff);
    if (sel) { int pos = atomicAdd(&counter, 1); selIdx[b * CAP + pos] = t; }
    selFlag[(size_t)b * Tq + t] = sel ? (unsigned char)1 : (unsigned char)0;
  }
  if (!takeAllEq) {                      // rare: exact ties at cutoff, lowest index first
    __syncthreads();
    if (tid == 0) {
      int taken = 0;
      for (int t = 0; t < Tq && taken < need; ++t) {
        unsigned long long u = (unsigned long long)__double_as_longlong(s[t]);
        unsigned long long k = (u >> 63) ? ~u : (u | 0x8000000000000000ULL);
        if (k == cutoff) {
          selIdx[b * CAP + gtTot + taken] = t;
          selFlag[(size_t)b * Tq + t] = 1;
          ++taken;
        }
      }
    }
  }
}

// ---------- gather selected rows -> bf16 Xs [Mq, Dq] ----------
__global__ void gather_kernel(const float* __restrict__ x,
                              const int* __restrict__ selIdx,
                              unsigned short* __restrict__ Xs) {
  int wid = threadIdx.x >> 6, lane = threadIdx.x & 63;
  int m = blockIdx.x * 4 + wid;          // [0, Mq)
  int b = m >> 12;                       // CAP == 4096
  int tok = selIdx[m];
  const float4* src = (const float4*)(x + ((size_t)b * Tq + tok) * Dq);
  ushort4* dst = (ushort4*)(Xs + (size_t)m * Dq);
#pragma unroll
  for (int q = 0; q < 4; ++q) {
    float4 v = src[lane + q * 64];
    ushort4 o; o.x = f2bf(v.x); o.y = f2bf(v.y); o.z = f2bf(v.z); o.w = f2bf(v.w);
    dst[lane + q * 64] = o;
  }
}

// ---------- pass-through copy of unselected rows ----------
__global__ void copy_pass(const float* __restrict__ x,
                          const unsigned char* __restrict__ selFlag,
                          float* __restrict__ out) {
  int wid = threadIdx.x >> 6, lane = threadIdx.x & 63;
  int row = blockIdx.x * 4 + wid;        // [0, B*T)
  if (selFlag[row]) return;              // wave-uniform branch
  const float4* src = (const float4*)(x + (size_t)row * Dq);
  float4* dst = (float4*)(out + (size_t)row * Dq);
#pragma unroll
  for (int q = 0; q < 4; ++q) dst[lane + q * 64] = src[lane + q * 64];
}

// ---------- fp32 [R,C] -> bf16 transposed [C,R] ----------
__global__ void transpose_f32_to_bf16(const float* __restrict__ in,
                                      unsigned short* __restrict__ out,
                                      int R, int C) {
  __shared__ float tile[32][33];
  int tx = threadIdx.x, ty = threadIdx.y;          // (32, 8)
  int c0 = blockIdx.x * 32, r0 = blockIdx.y * 32;
#pragma unroll
  for (int k = 0; k < 4; ++k)
    tile[ty + k * 8][tx] = in[(size_t)(r0 + ty + k * 8) * C + c0 + tx];
  __syncthreads();
#pragma unroll
  for (int k = 0; k < 4; ++k)
    out[(size_t)(c0 + ty + k * 8) * R + r0 + tx] = f2bf(tile[tx][ty + k * 8]);
}

// ============================================================================
// 256x256-tile, BK=64, 8-wave (2Mx4N), 8-phase schedule with counted vmcnt.
// R1 changes vs R0: (a) all ds_reads are precomputed-base + compile-time
// immediate (the kk-XOR only flips one swizzle bit -> two base pointers per
// operand); (b) staging addresses hoisted to one per-iteration base + const
// offsets; (c) template-faithful phase boundary: barrier; lgkmcnt(0);
// sched_barrier(0); setprio(1); 16xMFMA; setprio(0); barrier.
// ============================================================================

#define MFMA1(i, j, a, b) acc[i][j] = __builtin_amdgcn_mfma_f32_16x16x32_bf16(a, b, acc[i][j], 0, 0, 0)
#define MMQ(ib, jb, AF, BF) do { \
  MFMA1((ib)+0,(jb)+0,AF[0][0],BF[0][0]); MFMA1((ib)+0,(jb)+1,AF[0][0],BF[1][0]); \
  MFMA1((ib)+1,(jb)+0,AF[1][0],BF[0][0]); MFMA1((ib)+1,(jb)+1,AF[1][0],BF[1][0]); \
  MFMA1((ib)+2,(jb)+0,AF[2][0],BF[0][0]); MFMA1((ib)+2,(jb)+1,AF[2][0],BF[1][0]); \
  MFMA1((ib)+3,(jb)+0,AF[3][0],BF[0][0]); MFMA1((ib)+3,(jb)+1,AF[3][0],BF[1][0]); \
  MFMA1((ib)+0,(jb)+0,AF[0][1],BF[0][1]); MFMA1((ib)+0,(jb)+1,AF[0][1],BF[1][1]); \
  MFMA1((ib)+1,(jb)+0,AF[1][1],BF[0][1]); MFMA1((ib)+1,(jb)+1,AF[1][1],BF[1][1]); \
  MFMA1((ib)+2,(jb)+0,AF[2][1],BF[0][1]); MFMA1((ib)+2,(jb)+1,AF[2][1],BF[1][1]); \
  MFMA1((ib)+3,(jb)+0,AF[3][1],BF[0][1]); MFMA1((ib)+3,(jb)+1,AF[3][1],BF[1][1]); \
} while (0)

// ds_read: base pointer (kk selects the bit-5-XORed base) + compile-time imm
#define LDSA(dst, i, kk, bo) dst = *(const v8s*)(((kk) ? pA1 : pA0) + (bo) + (i) * 1024)
#define LDSB(dst, j, kk, bo) dst = *(const v8s*)(((kk) ? pB1 : pB0) + (bo) + (j) * 1024)

#define RD_A_LO(bo) do { LDSA(afr[0][0],0,0,bo); LDSA(afr[0][1],0,1,bo); \
                         LDSA(afr[1][0],1,0,bo); LDSA(afr[1][1],1,1,bo); \
                         LDSA(afr[2][0],2,0,bo); LDSA(afr[2][1],2,1,bo); \
                         LDSA(afr[3][0],3,0,bo); LDSA(afr[3][1],3,1,bo); } while (0)
#define RD_A_HI(bo) do { LDSA(afr[0][0],4,0,bo); LDSA(afr[0][1],4,1,bo); \
                         LDSA(afr[1][0],5,0,bo); LDSA(afr[1][1],5,1,bo); \
                         LDSA(afr[2][0],6,0,bo); LDSA(afr[2][1],6,1,bo); \
                         LDSA(afr[3][0],7,0,bo); LDSA(afr[3][1],7,1,bo); } while (0)
#define RD_B_LO(bo) do { LDSB(bfrA[0][0],0,0,bo); LDSB(bfrA[0][1],0,1,bo); \
                         LDSB(bfrA[1][0],1,0,bo); LDSB(bfrA[1][1],1,1,bo); } while (0)
#define RD_B_HI(bo) do { LDSB(bfrB[0][0],2,0,bo); LDSB(bfrB[0][1],2,1,bo); \
                         LDSB(bfrB[1][0],3,0,bo); LDSB(bfrB[1][1],3,1,bo); } while (0)

// staging: per-iteration base aIt/bIt (tile t0); rel/qtr are compile-time
#define STG_A(qtr, rel, bo) async_cp16(aIt + (size_t)((qtr) * 64 * K + (rel) * 64), aDst + (bo) + (qtr) * 4096)
#define STG_B(qtr, rel, bo) async_cp16(bIt + (size_t)((qtr) * 64 * K + (rel) * 64), bDst + (bo) + (qtr) * 4096)

#define BARR() __builtin_amdgcn_s_barrier()
#define WAITV(n) asm volatile("s_waitcnt vmcnt(" #n ")" ::: "memory")

// phase boundary: barrier -> drain LDS reads -> pin -> prioritized MFMA -> barrier
#define PH_MMQ(ib, jb, BF) do { \
  BARR(); \
  asm volatile("s_waitcnt lgkmcnt(0)" ::: "memory"); \
  __builtin_amdgcn_sched_barrier(0); \
  __builtin_amdgcn_s_setprio(1); MMQ(ib, jb, afr, BF); __builtin_amdgcn_s_setprio(0); \
  BARR(); \
} while (0)

template<int K, int NTN, bool IS_G1>
__global__ __launch_bounds__(512, 2)
void gemm_8ph(const unsigned short* __restrict__ A,   // [rows, K] bf16
              const unsigned short* __restrict__ Bt,  // [N, K] bf16
              const float* __restrict__ bias,
              unsigned short* __restrict__ Hout,      // IS_G1: [rows, Fq] bf16
              const int* __restrict__ selIdx,         // !IS_G1
              float* __restrict__ out,                // !IS_G1
              int chunkStart) {
  constexpr int NT = K / 64;   // K-tiles
  constexpr int NI = NT / 2;   // 8-phase iterations
  __shared__ __align__(16) unsigned short As[2 * 256 * 64];
  __shared__ __align__(16) unsigned short Bs[2 * 256 * 64];

  const int tid = threadIdx.x;
  const int wid = tid >> 6, lane = tid & 63;
  const int wm = wid >> 2, wn = wid & 3;          // 2 x 4 wave grid
  const int quad = lane >> 4, l16 = lane & 15;

  // bijective XCD swizzle (m204 variant; valid for any grid size)
  const int nwg = gridDim.x;
  const int qq = nwg >> 3, rr = nwg & 7;
  const int xcd = blockIdx.x & 7, loc = blockIdx.x >> 3;
  const int s = (xcd < rr ? xcd * (qq + 1) : rr * (qq + 1) + (xcd - rr) * qq) + loc;
  const int pIdx = s / NTN, nIdx = s % NTN;
  const int m0 = pIdx * 256, n0 = nIdx * 256;

  // ---- staging addressing (pre-swizzled global source, linear LDS dest) ----
  const int sr = tid >> 3;                        // row within 64-row quarter
  const int sc = (tid & 7) ^ (sr & 7);            // swizzled source 16B chunk
  const unsigned short* aSrc = A  + (size_t)(m0 + sr) * K + sc * 8;
  const unsigned short* bSrc = Bt + (size_t)(n0 + sr) * K + sc * 8;
  unsigned short* aDst = As + wid * 512;          // wave-uniform LDS base
  unsigned short* bDst = Bs + wid * 512;

  // ---- read addressing: row*64 + (chunk ^ (row&7))*8 shorts; kk flips bit 5
  const int swz = (quad ^ (l16 & 7)) * 8;
  const int aRdB = (wm * 128 + l16) * 64 + swz;
  const int bRdB = (wn * 64 + l16) * 64 + swz;
  const unsigned short* pA0 = As + aRdB;
  const unsigned short* pA1 = As + (aRdB ^ 32);
  const unsigned short* pB0 = Bs + bRdB;
  const unsigned short* pB1 = Bs + (bRdB ^ 32);

  v4f acc[8][4] = {};
  v8s afr[4][2], bfrA[2][2], bfrB[2][2];

  // ---- prologue: tile0 fully (8 loads, buf0); tile1 A-Q0,Q2 + B-Q0..Q3 (6, buf1)
  {
    const unsigned short* aIt = aSrc;
    const unsigned short* bIt = bSrc;
    STG_A(0, 0, 0); STG_A(1, 0, 0); STG_A(2, 0, 0); STG_A(3, 0, 0);
    STG_B(0, 0, 0); STG_B(1, 0, 0); STG_B(2, 0, 0); STG_B(3, 0, 0);
    STG_A(0, 1, 16384); STG_A(2, 1, 16384);
    STG_B(0, 1, 16384); STG_B(1, 1, 16384); STG_B(2, 1, 16384); STG_B(3, 1, 16384);
  }
  WAITV(6);            // tile0 resident; tile1's 6 may stay in flight
  BARR();

  // even tiles -> buf0 (bo=0), odd tiles -> buf1 (bo=16384): compile-time
  for (int it = 0; it < NI - 1; ++it) {
    const int t0 = 2 * it;
    const unsigned short* aIt = aSrc + (size_t)t0 * 64;
    const unsigned short* bIt = bSrc + (size_t)t0 * 64;
    // phase 0 (tile t0)
    RD_A_LO(0); RD_B_LO(0);
    STG_A(1, 1, 16384); STG_A(3, 1, 16384);
    PH_MMQ(0, 0, bfrA);
    // phase 1
    RD_B_HI(0);
    STG_A(0, 2, 0); STG_A(2, 2, 0);
    PH_MMQ(0, 2, bfrB);
    // phase 2
    RD_A_HI(0);
    STG_B(0, 2, 0); STG_B(1, 2, 0);
    PH_MMQ(4, 0, bfrA);
    // phase 3: counted wait -> tile t0+1 fully resident
    STG_B(2, 2, 0); STG_B(3, 2, 0);
    WAITV(6);
    PH_MMQ(4, 2, bfrB);
    // phase 4 (tile t0+1)
    RD_A_LO(16384); RD_B_LO(16384);
    STG_A(1, 2, 0); STG_A(3, 2, 0);
    PH_MMQ(0, 0, bfrA);
    // phase 5
    RD_B_HI(16384);
    STG_A(0, 3, 16384); STG_A(2, 3, 16384);
    PH_MMQ(0, 2, bfrB);
    // phase 6
    RD_A_HI(16384);
    STG_B(0, 3, 16384); STG_B(1, 3, 16384);
    PH_MMQ(4, 0, bfrA);
    // phase 7: counted wait -> tile t0+2 fully resident
    STG_B(2, 3, 16384); STG_B(3, 3, 16384);
    WAITV(6);
    PH_MMQ(4, 2, bfrB);
  }

  { // ---- last iteration: tiles NT-2 (buf0), NT-1 (buf1); drain ----
    const unsigned short* aIt = aSrc + (size_t)(NT - 2) * 64;
    const unsigned short* bIt = bSrc + (size_t)(NT - 2) * 64;
    RD_A_LO(0); RD_B_LO(0);
    STG_A(1, 1, 16384); STG_A(3, 1, 16384);   // final 2 quarters of tile NT-1
    PH_MMQ(0, 0, bfrA);
    RD_B_HI(0);
    PH_MMQ(0, 2, bfrB);
    RD_A_HI(0);
    PH_MMQ(4, 0, bfrA);
    WAITV(0);                                 // tile NT-1 resident
    PH_MMQ(4, 2, bfrB);
    RD_A_LO(16384); RD_B_LO(16384);
    PH_MMQ(0, 0, bfrA);
    RD_B_HI(16384);
    PH_MMQ(0, 2, bfrB);
    RD_A_HI(16384);
    PH_MMQ(4, 0, bfrA);
    asm volatile("s_waitcnt lgkmcnt(0)" ::: "memory");
    __builtin_amdgcn_sched_barrier(0);
    __builtin_amdgcn_s_setprio(1); MMQ(4, 2, afr, bfrB); __builtin_amdgcn_s_setprio(0);
  }

  // ---- epilogue ----
  const int mB = m0 + wm * 128, nB = n0 + wn * 64;
  float bv[4];
#pragma unroll
  for (int j = 0; j < 4; ++j) bv[j] = bias[nB + j * 16 + l16];

  if constexpr (IS_G1) {
    const float kA = 0.7978845608028654f, kB2 = 0.044715f * 0.7978845608028654f;
    const float kE = -2.0f * 1.4426950408889634f;   // exp(-2z) = exp2(kE*z)
#pragma unroll
    for (int i = 0; i < 8; ++i)
#pragma unroll
      for (int r = 0; r < 4; ++r) {
        const int row = mB + i * 16 + quad * 4 + r;
        unsigned short* hp = Hout + (size_t)row * Fq;
#pragma unroll
        for (int j = 0; j < 4; ++j) {
          float c = acc[i][j][r] + bv[j];
          float z = c * __builtin_fmaf(kB2, c * c, kA);
          float a = exp2f(kE * fabsf(z));
          float th = copysignf((1.0f - a) * __builtin_amdgcn_rcpf(1.0f + a), z);
          hp[nB + j * 16 + l16] = f2bf(0.5f * c * (1.0f + th));
        }
      }
  } else {
#pragma unroll
    for (int i = 0; i < 8; ++i)
#pragma unroll
      for (int r = 0; r < 4; ++r) {
        const int lrow = mB + i * 16 + quad * 4 + r;
        const int m = chunkStart + lrow;
        const int b = m >> 12;             // CAP == 4096
        const int tok = selIdx[m];
        float* op = out + ((size_t)b * Tq + tok) * Dq;
#pragma unroll
        for (int j = 0; j < 4; ++j)
          op[nB + j * 16 + l16] = acc[i][j][r] + bv[j];
      }
  }
}

// ---------- host ----------
extern "C" void kernel_launch(void* const* d_in, const int* in_sizes, int n_in,
                              void* d_out, int out_size, void* d_ws, size_t ws_size,
                              hipStream_t stream) {
  const float* x        = (const float*)d_in[0];
  const float* w_router = (const float*)d_in[1];
  const float* w1       = (const float*)d_in[2];
  const float* b1       = (const float*)d_in[3];
  const float* w2       = (const float*)d_in[4];
  const float* b2       = (const float*)d_in[5];
  float* out = (float*)d_out;

  char* p = (char*)d_ws;
  auto alloc = [&](size_t bytes) {
    char* r = p;
    p += (bytes + 255) & ~(size_t)255;
    return r;
  };
  double* scores          = (double*)alloc((size_t)Bq * Tq * 8);
  int* selIdx             = (int*)alloc((size_t)Mq * 4);
  unsigned char* selFlag  = (unsigned char*)alloc((size_t)Bq * Tq);
  unsigned short* W1t     = (unsigned short*)alloc((size_t)Dq * Fq * 2);  // [F, D]
  unsigned short* W2t     = (unsigned short*)alloc((size_t)Dq * Fq * 2);  // [D, F]
  unsigned short* Xs      = (unsigned short*)alloc((size_t)Mq * Dq * 2);  // [M, D]
  size_t used = (size_t)(p - (char*)d_ws);
  size_t rem = ws_size > used ? ws_size - used : 0;
  int chunkRows = (int)(rem / ((size_t)Fq * 2));
  chunkRows = (chunkRows / 256) * 256;
  if (chunkRows > Mq) chunkRows = Mq;
  if (chunkRows < 256) chunkRows = 256;   // requires ws_size >= ~51 MB
  unsigned short* H = (unsigned short*)p;  // [chunkRows, F] bf16

  transpose_f32_to_bf16<<<dim3(Fq / 32, Dq / 32), dim3(32, 8), 0, stream>>>(w1, W1t, Dq, Fq);
  transpose_f32_to_bf16<<<dim3(Dq / 32, Fq / 32), dim3(32, 8), 0, stream>>>(w2, W2t, Fq, Dq);
  scores_kernel<<<2048, 256, 0, stream>>>(x, w_router, scores);
  select_topk<<<Bq, 1024, 0, stream>>>(scores, selIdx, selFlag);
  gather_kernel<<<Mq / 4, 256, 0, stream>>>(x, selIdx, Xs);
  copy_pass<<<(Bq * Tq) / 4, 256, 0, stream>>>(x, selFlag, out);

  for (int r0 = 0; r0 < Mq; r0 += chunkRows) {
    int rows = (Mq - r0 < chunkRows) ? (Mq - r0) : chunkRows;
    int p1 = rows / 256;
    gemm_8ph<Dq, Fq / 256, true><<<p1 * (Fq / 256), 512, 0, stream>>>(
        Xs + (size_t)r0 * Dq, W1t, b1, H, nullptr, nullptr, 0);
    gemm_8ph<Fq, Dq / 256, false><<<p1 * (Dq / 256), 512, 0, stream>>>(
        H, W2t, b2, nullptr, selIdx, out, r0);
  }
}

// Round 3
// 612.968 us; speedup vs baseline: 1.1361x; 1.0054x over previous
//
#include <hip/hip_runtime.h>
#include <stdint.h>

typedef float v4f __attribute__((ext_vector_type(4)));
typedef short v8s __attribute__((ext_vector_type(8)));

constexpr int Bq = 4, Tq = 8192, Dq = 1024, Fq = 4096;
constexpr int CAP = Tq / 2;     // 4096 tokens selected per batch row
constexpr int Mq  = Bq * CAP;   // 16384 routed tokens total

// ---------- helpers ----------
__device__ __forceinline__ unsigned short f2bf(float f) {
  unsigned int u = __float_as_uint(f);
  u += 0x7FFFu + ((u >> 16) & 1u);   // RNE
  return (unsigned short)(u >> 16);
}

__device__ __forceinline__ void async_cp16(const void* g, void* l) {
  // 16B/lane global->LDS DMA; LDS dest is wave-uniform base + lane*16
  __builtin_amdgcn_global_load_lds(
      (__attribute__((address_space(1))) void*)g,
      (__attribute__((address_space(3))) void*)l, 16, 0, 0);
}

// ---------- scores: s[b,t] = dot(x[b,t,:], w_router), fp64 accumulate ----------
__global__ void scores_kernel(const float* __restrict__ x,
                              const float* __restrict__ wr_g,
                              double* __restrict__ scores) {
  __shared__ __align__(16) float wr[Dq];
  for (int i = threadIdx.x; i < Dq; i += 256) wr[i] = wr_g[i];
  __syncthreads();
  int wid = threadIdx.x >> 6, lane = threadIdx.x & 63;
  int gw = blockIdx.x * 4 + wid;
  const float4* wp = (const float4*)wr;
  for (int rr = 0; rr < 4; ++rr) {
    int row = gw * 4 + rr;   // [0, B*T)
    const float4* xp = (const float4*)(x + (size_t)row * Dq);
    double s = 0.0;
#pragma unroll
    for (int q = 0; q < 4; ++q) {
      float4 v = xp[lane + q * 64];
      float4 w = wp[lane + q * 64];
      s += (double)v.x * w.x + (double)v.y * w.y + (double)v.z * w.z + (double)v.w * w.w;
    }
#pragma unroll
    for (int off = 32; off; off >>= 1) s += __shfl_down(s, off);
    if (lane == 0) scores[row] = s;
  }
}

// ---------- top-k select (exact, per batch row) ----------
__device__ __forceinline__ int block_reduce_i(int v, int* red, int tid) {
#pragma unroll
  for (int off = 32; off; off >>= 1) v += __shfl_down(v, off);
  __syncthreads();                       // protect red[] from previous call
  if ((tid & 63) == 0) red[tid >> 6] = v;
  __syncthreads();
  int s = 0;
#pragma unroll
  for (int k = 0; k < 16; ++k) s += red[k];
  return s;                              // same value in all threads
}

__global__ __launch_bounds__(1024) void select_topk(const double* __restrict__ scores,
                                                    int* __restrict__ selIdx,
                                                    unsigned char* __restrict__ selFlag) {
  int b = blockIdx.x, tid = threadIdx.x;
  const double* s = scores + (size_t)b * Tq;
  __shared__ int red[16];
  __shared__ int counter;
  unsigned long long key[8];
#pragma unroll
  for (int i = 0; i < 8; ++i) {
    unsigned long long u = (unsigned long long)__double_as_longlong(s[tid + i * 1024]);
    key[i] = (u >> 63) ? ~u : (u | 0x8000000000000000ULL);  // order-preserving map
  }
  // cutoff = max X with count(key >= X) >= CAP  (== CAP-th largest key)
  unsigned long long cutoff = 0ULL;
  for (int bit = 63; bit >= 0; --bit) {
    unsigned long long cand = cutoff | (1ULL << bit);
    int c = 0;
#pragma unroll
    for (int i = 0; i < 8; ++i) c += (key[i] >= cand) ? 1 : 0;
    int tot = block_reduce_i(c, red, tid);
    if (tot >= CAP) cutoff = cand;
  }
  int cGt = 0, cEq = 0;
#pragma unroll
  for (int i = 0; i < 8; ++i) { cGt += (key[i] > cutoff); cEq += (key[i] == cutoff); }
  int gtTot = block_reduce_i(cGt, red, tid);
  int eqTot = block_reduce_i(cEq, red, tid);
  int need = CAP - gtTot;                // ties to take (>=1)
  if (tid == 0) counter = 0;
  __syncthreads();
  bool takeAllEq = (eqTot == need);      // common case: no straddling duplicates
#pragma unroll
  for (int i = 0; i < 8; ++i) {
    int t = tid + i * 1024;
    bool sel = takeAllEq ? (key[i] >= cutoff) : (key[i] > cutoff);
    if (sel) { int pos = atomicAdd(&counter, 1); selIdx[b * CAP + pos] = t; }
    selFlag[(size_t)b * Tq + t] = sel ? (unsigned char)1 : (unsigned char)0;
  }
  if (!takeAllEq) {                      // rare: exact ties at cutoff, lowest index first
    __syncthreads();
    if (tid == 0) {
      int taken = 0;
      for (int t = 0; t < Tq && taken < need; ++t) {
        unsigned long long u = (unsigned long long)__double_as_longlong(s[t]);
        unsigned long long k = (u >> 63) ? ~u : (u | 0x8000000000000000ULL);
        if (k == cutoff) {
          selIdx[b * CAP + gtTot + taken] = t;
          selFlag[(size_t)b * Tq + t] = 1;
          ++taken;
        }
      }
    }
  }
}

// ---------- gather selected rows -> bf16 Xs [Mq, Dq] ----------
__global__ void gather_kernel(const float* __restrict__ x,
                              const int* __restrict__ selIdx,
                              unsigned short* __restrict__ Xs) {
  int wid = threadIdx.x >> 6, lane = threadIdx.x & 63;
  int m = blockIdx.x * 4 + wid;          // [0, Mq)
  int b = m >> 12;                       // CAP == 4096
  int tok = selIdx[m];
  const float4* src = (const float4*)(x + ((size_t)b * Tq + tok) * Dq);
  ushort4* dst = (ushort4*)(Xs + (size_t)m * Dq);
#pragma unroll
  for (int q = 0; q < 4; ++q) {
    float4 v = src[lane + q * 64];
    ushort4 o; o.x = f2bf(v.x); o.y = f2bf(v.y); o.z = f2bf(v.z); o.w = f2bf(v.w);
    dst[lane + q * 64] = o;
  }
}

// ---------- pass-through copy of unselected rows ----------
__global__ void copy_pass(const float* __restrict__ x,
                          const unsigned char* __restrict__ selFlag,
                          float* __restrict__ out) {
  int wid = threadIdx.x >> 6, lane = threadIdx.x & 63;
  int row = blockIdx.x * 4 + wid;        // [0, B*T)
  if (selFlag[row]) return;              // wave-uniform branch
  const float4* src = (const float4*)(x + (size_t)row * Dq);
  float4* dst = (float4*)(out + (size_t)row * Dq);
#pragma unroll
  for (int q = 0; q < 4; ++q) dst[lane + q * 64] = src[lane + q * 64];
}

// ---------- fp32 [R,C] -> bf16 transposed [C,R] ----------
__global__ void transpose_f32_to_bf16(const float* __restrict__ in,
                                      unsigned short* __restrict__ out,
                                      int R, int C) {
  __shared__ float tile[32][33];
  int tx = threadIdx.x, ty = threadIdx.y;          // (32, 8)
  int c0 = blockIdx.x * 32, r0 = blockIdx.y * 32;
#pragma unroll
  for (int k = 0; k < 4; ++k)
    tile[ty + k * 8][tx] = in[(size_t)(r0 + ty + k * 8) * C + c0 + tx];
  __syncthreads();
#pragma unroll
  for (int k = 0; k < 4; ++k)
    out[(size_t)(c0 + ty + k * 8) * R + r0 + tx] = f2bf(tile[tx][ty + k * 8]);
}

// ============================================================================
// 256x256-tile, BK=64, 8-wave (2Mx4N), software-pipelined fragment reads.
// R2 structural change: ds_reads for quadrant k+1 are ISSUED BEFORE quadrant
// k's MFMA cluster and consumed a phase later (compiler inserts counted
// lgkmcnt), so LDS servicing overlaps MFMA execution. Split A fragments
// (afr0 = A-LO rows, afr1 = A-HI rows) so prefetch never overwrites live regs.
// 5 barriers/K-tile (one per phase + extra residency barrier at ph3).
// Staging safety (write-after-read, cross-wave, via end-of-phase barriers):
//   A-Q0,Q2 regions free after ph0 barrier (afr0 waited by Q00's MFMA)
//   all B regions free after ph1 barrier (bfrA@Q00, bfrB@Q02)
//   A-Q1,Q3 regions free after ph2 barrier (afr1 waited by Q40)
// Residency: per-wave WAITV(6) + collective barrier before next-tile reads
// (vmcnt is per-wave; the barrier makes all 8 waves' staging loads visible).
// ============================================================================

#define MFMA1(i, j, a, b) acc[i][j] = __builtin_amdgcn_mfma_f32_16x16x32_bf16(a, b, acc[i][j], 0, 0, 0)
#define MMQ(ib, jb, AF, BF) do { \
  MFMA1((ib)+0,(jb)+0,AF[0][0],BF[0][0]); MFMA1((ib)+0,(jb)+1,AF[0][0],BF[1][0]); \
  MFMA1((ib)+1,(jb)+0,AF[1][0],BF[0][0]); MFMA1((ib)+1,(jb)+1,AF[1][0],BF[1][0]); \
  MFMA1((ib)+2,(jb)+0,AF[2][0],BF[0][0]); MFMA1((ib)+2,(jb)+1,AF[2][0],BF[1][0]); \
  MFMA1((ib)+3,(jb)+0,AF[3][0],BF[0][0]); MFMA1((ib)+3,(jb)+1,AF[3][0],BF[1][0]); \
  MFMA1((ib)+0,(jb)+0,AF[0][1],BF[0][1]); MFMA1((ib)+0,(jb)+1,AF[0][1],BF[1][1]); \
  MFMA1((ib)+1,(jb)+0,AF[1][1],BF[0][1]); MFMA1((ib)+1,(jb)+1,AF[1][1],BF[1][1]); \
  MFMA1((ib)+2,(jb)+0,AF[2][1],BF[0][1]); MFMA1((ib)+2,(jb)+1,AF[2][1],BF[1][1]); \
  MFMA1((ib)+3,(jb)+0,AF[3][1],BF[0][1]); MFMA1((ib)+3,(jb)+1,AF[3][1],BF[1][1]); \
} while (0)

// ds_read: base pointer (kk selects the bit-5-XORed base) + compile-time imm
#define LA(dst, i, kk, bo) dst = *(const v8s*)(((kk) ? pA1 : pA0) + (bo) + (i) * 1024)
#define LB(dst, j, kk, bo) dst = *(const v8s*)(((kk) ? pB1 : pB0) + (bo) + (j) * 1024)

#define RD_A_LO(bo) do { LA(afr0[0][0],0,0,bo); LA(afr0[0][1],0,1,bo); \
                         LA(afr0[1][0],1,0,bo); LA(afr0[1][1],1,1,bo); \
                         LA(afr0[2][0],2,0,bo); LA(afr0[2][1],2,1,bo); \
                         LA(afr0[3][0],3,0,bo); LA(afr0[3][1],3,1,bo); } while (0)
#define RD_A_HI(bo) do { LA(afr1[0][0],4,0,bo); LA(afr1[0][1],4,1,bo); \
                         LA(afr1[1][0],5,0,bo); LA(afr1[1][1],5,1,bo); \
                         LA(afr1[2][0],6,0,bo); LA(afr1[2][1],6,1,bo); \
                         LA(afr1[3][0],7,0,bo); LA(afr1[3][1],7,1,bo); } while (0)
#define RD_B_LO(bo) do { LB(bfrA[0][0],0,0,bo); LB(bfrA[0][1],0,1,bo); \
                         LB(bfrA[1][0],1,0,bo); LB(bfrA[1][1],1,1,bo); } while (0)
#define RD_B_HI(bo) do { LB(bfrB[0][0],2,0,bo); LB(bfrB[0][1],2,1,bo); \
                         LB(bfrB[1][0],3,0,bo); LB(bfrB[1][1],3,1,bo); } while (0)

// staging: per-pair base aIt/bIt; rel/qtr are compile-time
#define STG_A(qtr, rel, bo) async_cp16(aIt + (size_t)((qtr) * 64 * K + (rel) * 64), aDst + (bo) + (qtr) * 4096)
#define STG_B(qtr, rel, bo) async_cp16(bIt + (size_t)((qtr) * 64 * K + (rel) * 64), bDst + (bo) + (qtr) * 4096)

#define SP1() __builtin_amdgcn_s_setprio(1)
#define SP0() __builtin_amdgcn_s_setprio(0)
#define SB0() __builtin_amdgcn_sched_barrier(0)
#define PHB() do { SB0(); __builtin_amdgcn_s_barrier(); SB0(); } while (0)
#define WAITV(n) asm volatile("s_waitcnt vmcnt(" #n ")" ::: "memory")

// One K-tile, 4 phases. bo = this tile's LDS byte offset (shorts), ot = other
// buffer. r1/r2 = tile-relative staging indices vs aIt/bIt base.
// doS1: stage A-Q1,Q3 of t+1; doS2: stage t+2's six; WV: vmcnt wait stmt;
// doNext: issue next tile's A-LO/B-LO reads after the residency barrier.
#define TILE(bo, ot, r1, r2, doS1, doS2, WV, doNext) do { \
  /* ph0: prefetch B-HI; Q00 */ \
  RD_B_HI(bo); \
  if (doS1) { STG_A(1, r1, ot); STG_A(3, r1, ot); } \
  SB0(); \
  SP1(); MMQ(0, 0, afr0, bfrA); SP0(); \
  PHB(); \
  /* ph1: prefetch A-HI; Q02 */ \
  RD_A_HI(bo); \
  if (doS2) { STG_A(0, r2, bo); STG_A(2, r2, bo); } \
  SB0(); \
  SP1(); MMQ(0, 2, afr0, bfrB); SP0(); \
  PHB(); \
  /* ph2: Q40 */ \
  if (doS2) { STG_B(0, r2, bo); STG_B(1, r2, bo); } \
  SB0(); \
  SP1(); MMQ(4, 0, afr1, bfrA); SP0(); \
  PHB(); \
  /* ph3: residency wait + next-tile prefetch; Q42 */ \
  if (doS2) { STG_B(2, r2, bo); STG_B(3, r2, bo); } \
  WV; \
  PHB(); \
  if (doNext) { RD_A_LO(ot); RD_B_LO(ot); } \
  SB0(); \
  SP1(); MMQ(4, 2, afr1, bfrB); SP0(); \
  PHB(); \
} while (0)

template<int K, int NTN, bool IS_G1>
__global__ __launch_bounds__(512, 2)
void gemm_8ph(const unsigned short* __restrict__ A,   // [rows, K] bf16
              const unsigned short* __restrict__ Bt,  // [N, K] bf16
              const float* __restrict__ bias,
              unsigned short* __restrict__ Hout,      // IS_G1: [rows, Fq] bf16
              const int* __restrict__ selIdx,         // !IS_G1
              float* __restrict__ out,                // !IS_G1
              int chunkStart) {
  constexpr int NT = K / 64;   // K-tiles (16 or 64)
  __shared__ __align__(16) unsigned short As[2 * 256 * 64];
  __shared__ __align__(16) unsigned short Bs[2 * 256 * 64];

  const int tid = threadIdx.x;
  const int wid = tid >> 6, lane = tid & 63;
  const int wm = wid >> 2, wn = wid & 3;          // 2 x 4 wave grid
  const int quad = lane >> 4, l16 = lane & 15;

  // bijective XCD swizzle (m204 variant; valid for any grid size)
  const int nwg = gridDim.x;
  const int qq = nwg >> 3, rr = nwg & 7;
  const int xcd = blockIdx.x & 7, loc = blockIdx.x >> 3;
  const int s = (xcd < rr ? xcd * (qq + 1) : rr * (qq + 1) + (xcd - rr) * qq) + loc;
  const int pIdx = s / NTN, nIdx = s % NTN;
  const int m0 = pIdx * 256, n0 = nIdx * 256;

  // ---- staging addressing (pre-swizzled global source, linear LDS dest) ----
  const int sr = tid >> 3;                        // row within 64-row quarter
  const int sc = (tid & 7) ^ (sr & 7);            // swizzled source 16B chunk
  const unsigned short* aSrc = A  + (size_t)(m0 + sr) * K + sc * 8;
  const unsigned short* bSrc = Bt + (size_t)(n0 + sr) * K + sc * 8;
  unsigned short* aDst = As + wid * 512;          // wave-uniform LDS base
  unsigned short* bDst = Bs + wid * 512;

  // ---- read addressing: row*64 + (chunk ^ (row&7))*8 shorts; kk flips bit 5
  const int swz = (quad ^ (l16 & 7)) * 8;
  const int aRdB = (wm * 128 + l16) * 64 + swz;
  const int bRdB = (wn * 64 + l16) * 64 + swz;
  const unsigned short* pA0 = As + aRdB;
  const unsigned short* pA1 = As + (aRdB ^ 32);
  const unsigned short* pB0 = Bs + bRdB;
  const unsigned short* pB1 = Bs + (bRdB ^ 32);

  v4f acc[8][4] = {};
  v8s afr0[4][2], afr1[4][2], bfrA[2][2], bfrB[2][2];

  // ---- prologue: tile0 fully (8, buf0); tile1 A-Q0,Q2 + B-Q0..3 (6, buf1)
  {
    const unsigned short* aIt = aSrc;
    const unsigned short* bIt = bSrc;
    STG_A(0, 0, 0); STG_A(1, 0, 0); STG_A(2, 0, 0); STG_A(3, 0, 0);
    STG_B(0, 0, 0); STG_B(1, 0, 0); STG_B(2, 0, 0); STG_B(3, 0, 0);
    STG_A(0, 1, 16384); STG_A(2, 1, 16384);
    STG_B(0, 1, 16384); STG_B(1, 1, 16384); STG_B(2, 1, 16384); STG_B(3, 1, 16384);
  }
  WAITV(6);            // own tile0 loads done
  PHB();               // collective: tile0 resident
  RD_A_LO(0); RD_B_LO(0);

  // ---- main loop: tile pairs; tiles 0..NT-3 full, NT-2/NT-1 peeled ----
  for (int it = 0; it < NT / 2 - 1; ++it) {
    const unsigned short* aIt = aSrc + (size_t)(2 * it) * 64;
    const unsigned short* bIt = bSrc + (size_t)(2 * it) * 64;
    TILE(0,     16384, 1, 2, true, true, WAITV(6), true);   // tile 2it   (buf0)
    TILE(16384, 0,     2, 3, true, true, WAITV(6), true);   // tile 2it+1 (buf1)
  }
  {
    const unsigned short* aIt = aSrc + (size_t)(NT - 2) * 64;
    const unsigned short* bIt = bSrc + (size_t)(NT - 2) * 64;
    TILE(0,     16384, 1, 0, true,  false, WAITV(0), true);  // tile NT-2
    TILE(16384, 0,     0, 0, false, false, (void)0,  false); // tile NT-1 (drain)
  }

  // ---- epilogue ----
  const int mB = m0 + wm * 128, nB = n0 + wn * 64;
  float bv[4];
#pragma unroll
  for (int j = 0; j < 4; ++j) bv[j] = bias[nB + j * 16 + l16];

  if constexpr (IS_G1) {
    const float kA = 0.7978845608028654f, kB2 = 0.044715f * 0.7978845608028654f;
    const float kE = -2.0f * 1.4426950408889634f;   // exp(-2z) = exp2(kE*z)
#pragma unroll
    for (int i = 0; i < 8; ++i)
#pragma unroll
      for (int r = 0; r < 4; ++r) {
        const int row = mB + i * 16 + quad * 4 + r;
        unsigned short* hp = Hout + (size_t)row * Fq;
#pragma unroll
        for (int j = 0; j < 4; ++j) {
          float c = acc[i][j][r] + bv[j];
          float z = c * __builtin_fmaf(kB2, c * c, kA);
          float a = exp2f(kE * fabsf(z));
          float th = copysignf((1.0f - a) * __builtin_amdgcn_rcpf(1.0f + a), z);
          hp[nB + j * 16 + l16] = f2bf(0.5f * c * (1.0f + th));
        }
      }
  } else {
#pragma unroll
    for (int i = 0; i < 8; ++i)
#pragma unroll
      for (int r = 0; r < 4; ++r) {
        const int lrow = mB + i * 16 + quad * 4 + r;
        const int m = chunkStart + lrow;
        const int b = m >> 12;             // CAP == 4096
        const int tok = selIdx[m];
        float* op = out + ((size_t)b * Tq + tok) * Dq;
#pragma unroll
        for (int j = 0; j < 4; ++j)
          op[nB + j * 16 + l16] = acc[i][j][r] + bv[j];
      }
  }
}

// ---------- host ----------
extern "C" void kernel_launch(void* const* d_in, const int* in_sizes, int n_in,
                              void* d_out, int out_size, void* d_ws, size_t ws_size,
                              hipStream_t stream) {
  const float* x        = (const float*)d_in[0];
  const float* w_router = (const float*)d_in[1];
  const float* w1       = (const float*)d_in[2];
  const float* b1       = (const float*)d_in[3];
  const float* w2       = (const float*)d_in[4];
  const float* b2       = (const float*)d_in[5];
  float* out = (float*)d_out;

  char* p = (char*)d_ws;
  auto alloc = [&](size_t bytes) {
    char* r = p;
    p += (bytes + 255) & ~(size_t)255;
    return r;
  };
  double* scores          = (double*)alloc((size_t)Bq * Tq * 8);
  int* selIdx             = (int*)alloc((size_t)Mq * 4);
  unsigned char* selFlag  = (unsigned char*)alloc((size_t)Bq * Tq);
  unsigned short* W1t     = (unsigned short*)alloc((size_t)Dq * Fq * 2);  // [F, D]
  unsigned short* W2t     = (unsigned short*)alloc((size_t)Dq * Fq * 2);  // [D, F]
  unsigned short* Xs      = (unsigned short*)alloc((size_t)Mq * Dq * 2);  // [M, D]
  size_t used = (size_t)(p - (char*)d_ws);
  size_t rem = ws_size > used ? ws_size - used : 0;
  int chunkRows = (int)(rem / ((size_t)Fq * 2));
  chunkRows = (chunkRows / 256) * 256;
  if (chunkRows > Mq) chunkRows = Mq;
  if (chunkRows < 256) chunkRows = 256;   // requires ws_size >= ~51 MB
  unsigned short* H = (unsigned short*)p;  // [chunkRows, F] bf16

  transpose_f32_to_bf16<<<dim3(Fq / 32, Dq / 32), dim3(32, 8), 0, stream>>>(w1, W1t, Dq, Fq);
  transpose_f32_to_bf16<<<dim3(Dq / 32, Fq / 32), dim3(32, 8), 0, stream>>>(w2, W2t, Fq, Dq);
  scores_kernel<<<2048, 256, 0, stream>>>(x, w_router, scores);
  select_topk<<<Bq, 1024, 0, stream>>>(scores, selIdx, selFlag);
  gather_kernel<<<Mq / 4, 256, 0, stream>>>(x, selIdx, Xs);
  copy_pass<<<(Bq * Tq) / 4, 256, 0, stream>>>(x, selFlag, out);

  for (int r0 = 0; r0 < Mq; r0 += chunkRows) {
    int rows = (Mq - r0 < chunkRows) ? (Mq - r0) : chunkRows;
    int p1 = rows / 256;
    gemm_8ph<Dq, Fq / 256, true><<<p1 * (Fq / 256), 512, 0, stream>>>(
        Xs + (size_t)r0 * Dq, W1t, b1, H, nullptr, nullptr, 0);
    gemm_8ph<Fq, Dq / 256, false><<<p1 * (Dq / 256), 512, 0, stream>>>(
        H, W2t, b2, nullptr, selIdx, out, r0);
  }
}